// Round 14
// baseline (279.211 us; speedup 1.0000x reference)
//
#include <hip/hip_runtime.h>
#include <math.h>

// Problem constants (from reference)
#define BATCH 4
#define HW 512
#define NPLANE (512 * 512)
#define NS 12288      // oversampled points per batch
#define NU 3072       // top-k uncertain selected
#define NR 1024       // random extra points
#define NP 4096       // total selected points per batch
#define CF_CH 64
#define CC_CH 128
#define CIN 192
#define HID 256
#define OUTC 4
#define M_TOT (BATCH * NP)  // 16384
#define GCH_SPLIT 8         // point-chunks per (batch, channel-group) in gather
#define CPB 4               // channels per gather block (64 % CPB == 0)

// ---------------------------------------------------------------------------
// Bit-exact replication of XLA:CPU's vectorized f32 expf (Cephes polynomial),
// strict per-op f32 rounding, no FMA. DO NOT TOUCH — top-k order depends on it.
// ---------------------------------------------------------------------------
__device__ __forceinline__ float xla_expf(float xin) {
  float x = fminf(fmaxf(xin, -88.3762626647949f), 88.3762626647950f);
  float fx = floorf(__fadd_rn(__fmul_rn(x, 1.44269504088896341f), 0.5f));
  float tmp = __fmul_rn(0.693359375f, fx);
  float z = __fmul_rn(-2.12194440e-4f, fx);
  x = __fsub_rn(__fsub_rn(x, tmp), z);
  float y = __fadd_rn(__fmul_rn(x, 1.9875691500E-4f), 1.3981999507E-3f);
  y = __fadd_rn(__fmul_rn(y, x), 8.3334519073E-3f);
  y = __fadd_rn(__fmul_rn(y, x), 4.1665795894E-2f);
  y = __fadd_rn(__fmul_rn(y, x), 1.6666665459E-1f);
  y = __fadd_rn(__fmul_rn(y, x), 5.0000001201E-1f);
  z = __fmul_rn(x, x);
  y = __fadd_rn(__fmul_rn(y, z), x);
  y = __fadd_rn(y, 1.0f);
  int n = (int)fx;
  float p2n = __int_as_float((n + 127) << 23);
  return __fmul_rn(y, p2n);
}

// ---------------------------------------------------------------------------
// K1: uncertainty at oversampled points fused with random-extra append
// (R7/R11/R12-verified, byte-identical).
// ---------------------------------------------------------------------------
__global__ void k_uncert_extra(const float* __restrict__ logits,
                               const float* __restrict__ rp,
                               const float* __restrict__ re,
                               float* __restrict__ u,
                               float* __restrict__ pts_out) {
  int gid = blockIdx.x * 256 + threadIdx.x;
  if (gid < BATCH * NS) {
    int b = gid / NS;
    float px = rp[(size_t)gid * 2 + 0];
    float py = rp[(size_t)gid * 2 + 1];
    const float* plane = logits + (size_t)b * OUTC * NPLANE;  // channel 0

    float x = __fsub_rn(__fmul_rn(px, 512.0f), 0.5f);
    float y = __fsub_rn(__fmul_rn(py, 512.0f), 0.5f);
    float x0f = floorf(x), y0f = floorf(y);
    float wx = __fsub_rn(x, x0f);
    float wy = __fsub_rn(y, y0f);
    int x0 = (int)x0f, y0 = (int)y0f;
    int x1 = x0 + 1, y1 = y0 + 1;
    bool vx0 = (x0 >= 0) & (x0 < HW);
    bool vx1 = (x1 >= 0) & (x1 < HW);
    bool vy0 = (y0 >= 0) & (y0 < HW);
    bool vy1 = (y1 >= 0) & (y1 < HW);
    float g00 = (vx0 && vy0) ? plane[y0 * HW + x0] : 0.0f;
    float g10 = (vx1 && vy0) ? plane[y0 * HW + x1] : 0.0f;
    float g01 = (vx0 && vy1) ? plane[y1 * HW + x0] : 0.0f;
    float g11 = (vx1 && vy1) ? plane[y1 * HW + x1] : 0.0f;
    float omx = __fsub_rn(1.0f, wx);
    float omy = __fsub_rn(1.0f, wy);
    float w00 = __fmul_rn(omx, omy);
    float w10 = __fmul_rn(wx, omy);
    float w01 = __fmul_rn(omx, wy);
    float w11 = __fmul_rn(wx, wy);
    float s = __fadd_rn(
        __fadd_rn(__fadd_rn(__fmul_rn(g00, w00), __fmul_rn(g10, w10)),
                  __fmul_rn(g01, w01)),
        __fmul_rn(g11, w11));
    float e = xla_expf(-s);
    float sig = __fdiv_rn(1.0f, __fadd_rn(1.0f, e));
    float t = __fmul_rn(fabsf(__fsub_rn(sig, 0.5f)), 2.0f);
    u[gid] = __fsub_rn(1.0f, t);
  } else {
    int g = gid - BATCH * NS;  // [0, BATCH*NR)
    if (g < BATCH * NR) {
      int b = g / NR, j = g - b * NR;
      pts_out[((size_t)b * NP + NU + j) * 2 + 0] = re[(size_t)g * 2 + 0];
      pts_out[((size_t)b * NP + NU + j) * 2 + 1] = re[(size_t)g * 2 + 1];
    }
  }
}

// ---------------------------------------------------------------------------
// K2: exact stable top-k via ranking (R6-verified, byte-identical). CLOSED.
// ---------------------------------------------------------------------------
__global__ __launch_bounds__(256) void k_select(const float* __restrict__ u,
                                                const float* __restrict__ rp,
                                                float* __restrict__ pts_out) {
  __shared__ __align__(16) float su[NS];
  int b = blockIdx.x / (NS / 256);
  int blk = blockIdx.x % (NS / 256);
  const float* ub = u + (size_t)b * NS;
  for (int t = threadIdx.x; t < NS / 4; t += 256)
    ((float4*)su)[t] = ((const float4*)ub)[t];
  __syncthreads();
  int i = blk * 256 + (int)threadIdx.x;
  int wb = i & ~63;  // wave-uniform (blk*256 is 64-aligned)
  float ui = su[i];
  int r0 = 0, r1 = 0, r2 = 0, r3 = 0;
  for (int j = 0; j < wb; j += 8) {
    float4 v = *(const float4*)&su[j];
    float4 w = *(const float4*)&su[j + 4];
    r0 += (v.x >= ui) + (w.x >= ui);
    r1 += (v.y >= ui) + (w.y >= ui);
    r2 += (v.z >= ui) + (w.z >= ui);
    r3 += (v.w >= ui) + (w.w >= ui);
  }
  for (int j = wb; j < wb + 64; ++j) {
    float vj = su[j];
    r0 += (vj > ui) || (vj == ui && j < i);
  }
  for (int j = wb + 64; j < NS; j += 8) {
    float4 v = *(const float4*)&su[j];
    float4 w = *(const float4*)&su[j + 4];
    r0 += (v.x > ui) + (w.x > ui);
    r1 += (v.y > ui) + (w.y > ui);
    r2 += (v.z > ui) + (w.z > ui);
    r3 += (v.w > ui) + (w.w > ui);
  }
  int rank = (r0 + r1) + (r2 + r3);
  if (rank < NU) {
    pts_out[((size_t)b * NP + rank) * 2 + 0] = rp[((size_t)b * NS + i) * 2 + 0];
    pts_out[((size_t)b * NP + rank) * 2 + 1] = rp[((size_t)b * NS + i) * 2 + 1];
  }
}

// ---------------------------------------------------------------------------
// K3: fused metadata + row-sort + sorted materialization (R12-verified,
// byte-identical).
// ---------------------------------------------------------------------------
__global__ __launch_bounds__(512) void k_meta(const float* __restrict__ pts,
                                              int2* __restrict__ m2s,
                                              float4* __restrict__ wtss,
                                              int* __restrict__ perm) {
  __shared__ int2 marr[NP];  // 32 KB
  __shared__ int hist[512], pref[512];
  int b = blockIdx.x, tid = threadIdx.x;
  hist[tid] = 0;
  __syncthreads();
  float pxr[8], pyr[8];
#pragma unroll
  for (int q = 0; q < 8; ++q) {
    int p = q * 512 + tid;
    float px = pts[((size_t)b * NP + p) * 2 + 0];
    float py = pts[((size_t)b * NP + p) * 2 + 1];
    pxr[q] = px;
    pyr[q] = py;
    float x = px * 512.0f - 0.5f;
    float y = py * 512.0f - 0.5f;
    float x0f = floorf(x), y0f = floorf(y);
    int x0 = (int)x0f, y0 = (int)y0f;
    bool vx0 = (unsigned)x0 < (unsigned)HW;
    bool vx1 = (unsigned)(x0 + 1) < (unsigned)HW;
    bool vy0 = (unsigned)y0 < (unsigned)HW;
    bool vy1 = (unsigned)(y0 + 1) < (unsigned)HW;
    int vm = (int)(vx0 && vy0) | ((int)(vx1 && vy0) << 1) |
             ((int)(vx0 && vy1) << 2) | ((int)(vx1 && vy1) << 3);
    int i00 = y0 * HW + x0;
    marr[p] = make_int2(i00, vm);
    int key = min(max(i00, 0), NPLANE - 1) >> 9;
    atomicAdd(&hist[key], 1);
  }
  __syncthreads();
  int v = hist[tid];
  pref[tid] = v;
  __syncthreads();
  for (int d = 1; d < 512; d <<= 1) {
    int t = (tid >= d) ? pref[tid - d] : 0;
    __syncthreads();
    pref[tid] += t;
    __syncthreads();
  }
  hist[tid] = pref[tid] - v;  // exclusive prefix -> running offsets
  __syncthreads();
#pragma unroll
  for (int q = 0; q < 8; ++q) {
    int p = q * 512 + tid;
    int2 mm = marr[p];
    int key = min(max(mm.x, 0), NPLANE - 1) >> 9;
    int pos = atomicAdd(&hist[key], 1);
    perm[(size_t)b * NP + pos] = p;
    m2s[(size_t)b * NP + pos] = mm;
    float x = pxr[q] * 512.0f - 0.5f;
    float y = pyr[q] * 512.0f - 0.5f;
    float wx = x - floorf(x), wy = y - floorf(y);
    wtss[(size_t)b * NP + pos] =
        make_float4((1.0f - wx) * (1.0f - wy), wx * (1.0f - wy),
                    (1.0f - wx) * wy, wx * wy);
  }
}

// ---------------------------------------------------------------------------
// K4: gather, CPB=4 channels per block — metadata (m2s/wtss, 24 B/point) is
// loaded ONCE and reused for 4 planes (75 MB -> 19 MB of metadata traffic,
// ~30% fewer VMEM instrs). Fine/coarse boundary (c=64) is CPB-aligned so no
// block straddles; planes[] indexed only by compile-time-unrolled cc.
// Interior fast path (vm==15) per R13; taps/weights/sum order bit-identical.
// ---------------------------------------------------------------------------
__global__ __launch_bounds__(256) void k_gather7(
    const float* __restrict__ fine, const float* __restrict__ coarse,
    const int2* __restrict__ m2s, const float4* __restrict__ wtss,
    float* __restrict__ featsT) {
  int cgrp = blockIdx.x % (CIN / CPB);
  int rem = blockIdx.x / (CIN / CPB);
  int b = rem & (BATCH - 1);
  int part = rem >> 2;
  int c0 = cgrp * CPB;
  const float* planes[CPB];
#pragma unroll
  for (int cc = 0; cc < CPB; ++cc) {
    int c = c0 + cc;
    planes[cc] = (c < CF_CH)
                     ? fine + ((size_t)b * CF_CH + c) * NPLANE
                     : coarse + ((size_t)b * CC_CH + (c - CF_CH)) * NPLANE;
  }
  const int2* m2b = m2s + (size_t)b * NP;
  const float4* wtsb = wtss + (size_t)b * NP;
  float* outbase = featsT + (size_t)c0 * M_TOT + (size_t)b * NP;
  int s0 = part * (NP / GCH_SPLIT);
#pragma unroll
  for (int q = 0; q < NP / GCH_SPLIT / 256; ++q) {
    int s = s0 + q * 256 + (int)threadIdx.x;
    int2 mm = m2b[s];
    float4 w = wtsb[s];
    if (mm.y == 15) {
#pragma unroll
      for (int cc = 0; cc < CPB; ++cc) {
        const float* plane = planes[cc];
        float2 ra, rb;
        __builtin_memcpy(&ra, &plane[mm.x], 8);
        __builtin_memcpy(&rb, &plane[mm.x + HW], 8);
        float r = (((ra.x * w.x) + (ra.y * w.y)) + (rb.x * w.z)) + (rb.y * w.w);
        outbase[(size_t)cc * M_TOT + s] = r;
      }
    } else {
#pragma unroll
      for (int cc = 0; cc < CPB; ++cc) {
        const float* bp = planes[cc] + mm.x;
        float t00 = 0.0f, t10 = 0.0f, t01 = 0.0f, t11 = 0.0f;
        if (mm.y & 1) t00 = bp[0] * w.x;
        if (mm.y & 2) t10 = bp[1] * w.y;
        if (mm.y & 4) t01 = bp[HW] * w.z;
        if (mm.y & 8) t11 = bp[HW + 1] * w.w;
        outbase[(size_t)cc * M_TOT + s] = ((t00 + t10) + t01) + t11;
      }
    }
  }
}

// ---------------------------------------------------------------------------
// K5: GEMM layer 1 from transposed A (At[k][m]), C[M][256] row-major.
// 128x64 tile, BK=32, 256 threads, 8x4 acc. (R13-verified, byte-identical.)
// ---------------------------------------------------------------------------
__global__ __launch_bounds__(256) void k_gemm1_At(const float* __restrict__ At,
                                                  const float* __restrict__ W,
                                                  const float* __restrict__ bias,
                                                  float* __restrict__ C) {
  __shared__ __align__(16) float As[32][132];
  __shared__ __align__(16) float Bs[32][68];
  const int bx = blockIdx.x & 3;   // N tile (256/64)
  const int by = blockIdx.x >> 2;  // M tile (16384/128)
  const int tid = threadIdx.x;
  const int tn = tid & 15, tm = tid >> 4;
  const int m_base = by * 128, n_base = bx * 64;
  float acc[8][4] = {};
  for (int k0 = 0; k0 < CIN; k0 += 32) {
#pragma unroll
    for (int r = 0; r < 4; ++r) {  // A: 32k x 128m = 1024 float4
      int t = tid + r * 256;
      int kk = t >> 5, mg = (t & 31) * 4;
      *(float4*)&As[kk][mg] =
          *(const float4*)&At[(size_t)(k0 + kk) * M_TOT + m_base + mg];
    }
#pragma unroll
    for (int r = 0; r < 2; ++r) {  // B: 64n x 32k
      int t = tid + r * 256;
      int row = t >> 3, cg = (t & 7) * 4;
      float4 vw = *(const float4*)&W[(size_t)(n_base + row) * CIN + k0 + cg];
      Bs[cg + 0][row] = vw.x;
      Bs[cg + 1][row] = vw.y;
      Bs[cg + 2][row] = vw.z;
      Bs[cg + 3][row] = vw.w;
    }
    __syncthreads();
#pragma unroll
    for (int kk = 0; kk < 32; ++kk) {
      float a[8];
      *(float4*)&a[0] = *(const float4*)&As[kk][tm * 8];
      *(float4*)&a[4] = *(const float4*)&As[kk][tm * 8 + 4];
      float4 b4 = *(const float4*)&Bs[kk][tn * 4];
      float bw[4] = {b4.x, b4.y, b4.z, b4.w};
#pragma unroll
      for (int i = 0; i < 8; ++i)
#pragma unroll
        for (int j = 0; j < 4; ++j) acc[i][j] = fmaf(a[i], bw[j], acc[i][j]);
    }
    __syncthreads();
  }
  float bs[4];
#pragma unroll
  for (int j = 0; j < 4; ++j) bs[j] = bias[n_base + tn * 4 + j];
#pragma unroll
  for (int i = 0; i < 8; ++i) {
    float4 o;
    o.x = fmaxf(acc[i][0] + bs[0], 0.0f);
    o.y = fmaxf(acc[i][1] + bs[1], 0.0f);
    o.z = fmaxf(acc[i][2] + bs[2], 0.0f);
    o.w = fmaxf(acc[i][3] + bs[3], 0.0f);
    *(float4*)&C[(size_t)(m_base + tm * 8 + i) * HID + n_base + tn * 4] = o;
  }
}

// ---------------------------------------------------------------------------
// K6: GEMM layer 2 (row-major A), 128x64 tile, 8x4 acc. (R13-verified,
// byte-identical.)
// ---------------------------------------------------------------------------
template <int K>
__global__ __launch_bounds__(256) void k_gemm_relu(const float* __restrict__ A,
                                                   const float* __restrict__ W,
                                                   const float* __restrict__ bias,
                                                   float* __restrict__ C) {
  __shared__ __align__(16) float As[32][132];
  __shared__ __align__(16) float Bs[32][68];
  const int bx = blockIdx.x & 3;
  const int by = blockIdx.x >> 2;
  const int tid = threadIdx.x;
  const int tn = tid & 15, tm = tid >> 4;
  const int m_base = by * 128, n_base = bx * 64;
  float acc[8][4] = {};
  for (int k0 = 0; k0 < K; k0 += 32) {
#pragma unroll
    for (int r = 0; r < 4; ++r) {  // A: 128 rows x 32 k
      int t = tid + r * 256;
      int row = t >> 3, cg = (t & 7) * 4;
      float4 va = *(const float4*)&A[(size_t)(m_base + row) * K + k0 + cg];
      As[cg + 0][row] = va.x;
      As[cg + 1][row] = va.y;
      As[cg + 2][row] = va.z;
      As[cg + 3][row] = va.w;
    }
#pragma unroll
    for (int r = 0; r < 2; ++r) {  // B: 64n x 32k
      int t = tid + r * 256;
      int row = t >> 3, cg = (t & 7) * 4;
      float4 vw = *(const float4*)&W[(size_t)(n_base + row) * K + k0 + cg];
      Bs[cg + 0][row] = vw.x;
      Bs[cg + 1][row] = vw.y;
      Bs[cg + 2][row] = vw.z;
      Bs[cg + 3][row] = vw.w;
    }
    __syncthreads();
#pragma unroll
    for (int kk = 0; kk < 32; ++kk) {
      float a[8];
      *(float4*)&a[0] = *(const float4*)&As[kk][tm * 8];
      *(float4*)&a[4] = *(const float4*)&As[kk][tm * 8 + 4];
      float4 b4 = *(const float4*)&Bs[kk][tn * 4];
      float bw[4] = {b4.x, b4.y, b4.z, b4.w};
#pragma unroll
      for (int i = 0; i < 8; ++i)
#pragma unroll
        for (int j = 0; j < 4; ++j) acc[i][j] = fmaf(a[i], bw[j], acc[i][j]);
    }
    __syncthreads();
  }
  float bs[4];
#pragma unroll
  for (int j = 0; j < 4; ++j) bs[j] = bias[n_base + tn * 4 + j];
#pragma unroll
  for (int i = 0; i < 8; ++i) {
    float4 o;
    o.x = fmaxf(acc[i][0] + bs[0], 0.0f);
    o.y = fmaxf(acc[i][1] + bs[1], 0.0f);
    o.z = fmaxf(acc[i][2] + bs[2], 0.0f);
    o.w = fmaxf(acc[i][3] + bs[3], 0.0f);
    *(float4*)&C[(size_t)(m_base + tm * 8 + i) * HID + n_base + tn * 4] = o;
  }
}

// ---------------------------------------------------------------------------
// K7: final layer, 4 outputs per point, shuffle reduce; un-permutes sorted
// order on the output scatter (R9/R12-verified, byte-identical).
// ---------------------------------------------------------------------------
__global__ __launch_bounds__(256) void k_out(const float* __restrict__ h,
                                             const float* __restrict__ W3,
                                             const float* __restrict__ b3,
                                             const int* __restrict__ perm,
                                             float* __restrict__ out) {
  int gp = blockIdx.x * 4 + (threadIdx.x >> 6);
  int lane = threadIdx.x & 63;
  const float* hr = h + (size_t)gp * HID;
  float4 hv = *(const float4*)&hr[lane * 4];
  float s[4];
#pragma unroll
  for (int o = 0; o < 4; ++o) {
    float4 w = *(const float4*)&W3[o * HID + lane * 4];
    s[o] = hv.x * w.x + hv.y * w.y + hv.z * w.z + hv.w * w.w;
  }
#pragma unroll
  for (int off = 32; off; off >>= 1)
#pragma unroll
    for (int o = 0; o < 4; ++o) s[o] += __shfl_xor(s[o], off, 64);
  if (lane == 0) {
    int b = gp / NP, ns = gp % NP;
    int n = perm[(size_t)b * NP + ns];
#pragma unroll
    for (int o = 0; o < 4; ++o)
      out[((size_t)b * OUTC + o) * NP + n] = s[o] + b3[o];
  }
}

extern "C" void kernel_launch(void* const* d_in, const int* in_sizes, int n_in,
                              void* d_out, int out_size, void* d_ws, size_t ws_size,
                              hipStream_t stream) {
  const float* fine = (const float*)d_in[0];
  const float* coarse = (const float*)d_in[1];
  const float* logits = (const float*)d_in[2];
  const float* rand_points = (const float*)d_in[3];
  const float* rand_extra = (const float*)d_in[4];
  const float* W1 = (const float*)d_in[5];
  const float* b1 = (const float*)d_in[6];
  const float* W2 = (const float*)d_in[7];
  const float* b2 = (const float*)d_in[8];
  const float* W3 = (const float*)d_in[9];
  const float* b3 = (const float*)d_in[10];
  float* out = (float*)d_out;

  float* out_logits = out;
  float* out_points = out + (size_t)BATCH * OUTC * NP;

  // ws layout (bytes): u | m2s | wtss | perm | featsT | h1 | h2
  char* ws = (char*)d_ws;
  float* u = (float*)(ws + 0);               // 196608
  int2* m2s = (int2*)(ws + 196608);          // 131072
  float4* wtss = (float4*)(ws + 327680);     // 262144
  int* perm = (int*)(ws + 589824);           // 65536
  float* featsT = (float*)(ws + 655360);     // 12582912
  float* h1 = (float*)(ws + 13238272);       // 16777216
  float* h2 = (float*)(ws + 30015488);       // 16777216

  k_uncert_extra<<<(BATCH * NS + BATCH * NR + 255) / 256, 256, 0, stream>>>(
      logits, rand_points, rand_extra, u, out_points);
  k_select<<<BATCH * (NS / 256), 256, 0, stream>>>(u, rand_points, out_points);
  k_meta<<<BATCH, 512, 0, stream>>>(out_points, m2s, wtss, perm);
  k_gather7<<<(CIN / CPB) * BATCH * GCH_SPLIT, 256, 0, stream>>>(
      fine, coarse, m2s, wtss, featsT);
  k_gemm1_At<<<(M_TOT / 128) * 4, 256, 0, stream>>>(featsT, W1, b1, h1);
  k_gemm_relu<HID><<<(M_TOT / 128) * 4, 256, 0, stream>>>(h1, W2, b2, h2);
  k_out<<<M_TOT / 4, 256, 0, stream>>>(h2, W3, b3, perm, out_logits);
}

// Round 15
// 273.378 us; speedup vs baseline: 1.0213x; 1.0213x over previous
//
#include <hip/hip_runtime.h>
#include <math.h>

// Problem constants (from reference)
#define BATCH 4
#define HW 512
#define NPLANE (512 * 512)
#define NS 12288      // oversampled points per batch
#define NU 3072       // top-k uncertain selected
#define NR 1024       // random extra points
#define NP 4096       // total selected points per batch
#define CF_CH 64
#define CC_CH 128
#define CIN 192
#define HID 256
#define OUTC 4
#define M_TOT (BATCH * NP)  // 16384
#define GCH_SPLIT 8         // point-chunks per (batch, channel) in gather

// ---------------------------------------------------------------------------
// Bit-exact replication of XLA:CPU's vectorized f32 expf (Cephes polynomial),
// strict per-op f32 rounding, no FMA. DO NOT TOUCH — top-k order depends on it.
// ---------------------------------------------------------------------------
__device__ __forceinline__ float xla_expf(float xin) {
  float x = fminf(fmaxf(xin, -88.3762626647949f), 88.3762626647950f);
  float fx = floorf(__fadd_rn(__fmul_rn(x, 1.44269504088896341f), 0.5f));
  float tmp = __fmul_rn(0.693359375f, fx);
  float z = __fmul_rn(-2.12194440e-4f, fx);
  x = __fsub_rn(__fsub_rn(x, tmp), z);
  float y = __fadd_rn(__fmul_rn(x, 1.9875691500E-4f), 1.3981999507E-3f);
  y = __fadd_rn(__fmul_rn(y, x), 8.3334519073E-3f);
  y = __fadd_rn(__fmul_rn(y, x), 4.1665795894E-2f);
  y = __fadd_rn(__fmul_rn(y, x), 1.6666665459E-1f);
  y = __fadd_rn(__fmul_rn(y, x), 5.0000001201E-1f);
  z = __fmul_rn(x, x);
  y = __fadd_rn(__fmul_rn(y, z), x);
  y = __fadd_rn(y, 1.0f);
  int n = (int)fx;
  float p2n = __int_as_float((n + 127) << 23);
  return __fmul_rn(y, p2n);
}

// ---------------------------------------------------------------------------
// K1: uncertainty at oversampled points fused with random-extra append
// (R7/R11/R12-verified, byte-identical).
// ---------------------------------------------------------------------------
__global__ void k_uncert_extra(const float* __restrict__ logits,
                               const float* __restrict__ rp,
                               const float* __restrict__ re,
                               float* __restrict__ u,
                               float* __restrict__ pts_out) {
  int gid = blockIdx.x * 256 + threadIdx.x;
  if (gid < BATCH * NS) {
    int b = gid / NS;
    float px = rp[(size_t)gid * 2 + 0];
    float py = rp[(size_t)gid * 2 + 1];
    const float* plane = logits + (size_t)b * OUTC * NPLANE;  // channel 0

    float x = __fsub_rn(__fmul_rn(px, 512.0f), 0.5f);
    float y = __fsub_rn(__fmul_rn(py, 512.0f), 0.5f);
    float x0f = floorf(x), y0f = floorf(y);
    float wx = __fsub_rn(x, x0f);
    float wy = __fsub_rn(y, y0f);
    int x0 = (int)x0f, y0 = (int)y0f;
    int x1 = x0 + 1, y1 = y0 + 1;
    bool vx0 = (x0 >= 0) & (x0 < HW);
    bool vx1 = (x1 >= 0) & (x1 < HW);
    bool vy0 = (y0 >= 0) & (y0 < HW);
    bool vy1 = (y1 >= 0) & (y1 < HW);
    float g00 = (vx0 && vy0) ? plane[y0 * HW + x0] : 0.0f;
    float g10 = (vx1 && vy0) ? plane[y0 * HW + x1] : 0.0f;
    float g01 = (vx0 && vy1) ? plane[y1 * HW + x0] : 0.0f;
    float g11 = (vx1 && vy1) ? plane[y1 * HW + x1] : 0.0f;
    float omx = __fsub_rn(1.0f, wx);
    float omy = __fsub_rn(1.0f, wy);
    float w00 = __fmul_rn(omx, omy);
    float w10 = __fmul_rn(wx, omy);
    float w01 = __fmul_rn(omx, wy);
    float w11 = __fmul_rn(wx, wy);
    float s = __fadd_rn(
        __fadd_rn(__fadd_rn(__fmul_rn(g00, w00), __fmul_rn(g10, w10)),
                  __fmul_rn(g01, w01)),
        __fmul_rn(g11, w11));
    float e = xla_expf(-s);
    float sig = __fdiv_rn(1.0f, __fadd_rn(1.0f, e));
    float t = __fmul_rn(fabsf(__fsub_rn(sig, 0.5f)), 2.0f);
    u[gid] = __fsub_rn(1.0f, t);
  } else {
    int g = gid - BATCH * NS;  // [0, BATCH*NR)
    if (g < BATCH * NR) {
      int b = g / NR, j = g - b * NR;
      pts_out[((size_t)b * NP + NU + j) * 2 + 0] = re[(size_t)g * 2 + 0];
      pts_out[((size_t)b * NP + NU + j) * 2 + 1] = re[(size_t)g * 2 + 1];
    }
  }
}

// ---------------------------------------------------------------------------
// K2: exact stable top-k via ranking (R6-verified, byte-identical). CLOSED.
// ---------------------------------------------------------------------------
__global__ __launch_bounds__(256) void k_select(const float* __restrict__ u,
                                                const float* __restrict__ rp,
                                                float* __restrict__ pts_out) {
  __shared__ __align__(16) float su[NS];
  int b = blockIdx.x / (NS / 256);
  int blk = blockIdx.x % (NS / 256);
  const float* ub = u + (size_t)b * NS;
  for (int t = threadIdx.x; t < NS / 4; t += 256)
    ((float4*)su)[t] = ((const float4*)ub)[t];
  __syncthreads();
  int i = blk * 256 + (int)threadIdx.x;
  int wb = i & ~63;  // wave-uniform (blk*256 is 64-aligned)
  float ui = su[i];
  int r0 = 0, r1 = 0, r2 = 0, r3 = 0;
  for (int j = 0; j < wb; j += 8) {
    float4 v = *(const float4*)&su[j];
    float4 w = *(const float4*)&su[j + 4];
    r0 += (v.x >= ui) + (w.x >= ui);
    r1 += (v.y >= ui) + (w.y >= ui);
    r2 += (v.z >= ui) + (w.z >= ui);
    r3 += (v.w >= ui) + (w.w >= ui);
  }
  for (int j = wb; j < wb + 64; ++j) {
    float vj = su[j];
    r0 += (vj > ui) || (vj == ui && j < i);
  }
  for (int j = wb + 64; j < NS; j += 8) {
    float4 v = *(const float4*)&su[j];
    float4 w = *(const float4*)&su[j + 4];
    r0 += (v.x > ui) + (w.x > ui);
    r1 += (v.y > ui) + (w.y > ui);
    r2 += (v.z > ui) + (w.z > ui);
    r3 += (v.w > ui) + (w.w > ui);
  }
  int rank = (r0 + r1) + (r2 + r3);
  if (rank < NU) {
    pts_out[((size_t)b * NP + rank) * 2 + 0] = rp[((size_t)b * NS + i) * 2 + 0];
    pts_out[((size_t)b * NP + rank) * 2 + 1] = rp[((size_t)b * NS + i) * 2 + 1];
  }
}

// ---------------------------------------------------------------------------
// K3: fused metadata + row-sort + sorted materialization (R12-verified,
// byte-identical).
// ---------------------------------------------------------------------------
__global__ __launch_bounds__(512) void k_meta(const float* __restrict__ pts,
                                              int2* __restrict__ m2s,
                                              float4* __restrict__ wtss,
                                              int* __restrict__ perm) {
  __shared__ int2 marr[NP];  // 32 KB
  __shared__ int hist[512], pref[512];
  int b = blockIdx.x, tid = threadIdx.x;
  hist[tid] = 0;
  __syncthreads();
  float pxr[8], pyr[8];
#pragma unroll
  for (int q = 0; q < 8; ++q) {
    int p = q * 512 + tid;
    float px = pts[((size_t)b * NP + p) * 2 + 0];
    float py = pts[((size_t)b * NP + p) * 2 + 1];
    pxr[q] = px;
    pyr[q] = py;
    float x = px * 512.0f - 0.5f;
    float y = py * 512.0f - 0.5f;
    float x0f = floorf(x), y0f = floorf(y);
    int x0 = (int)x0f, y0 = (int)y0f;
    bool vx0 = (unsigned)x0 < (unsigned)HW;
    bool vx1 = (unsigned)(x0 + 1) < (unsigned)HW;
    bool vy0 = (unsigned)y0 < (unsigned)HW;
    bool vy1 = (unsigned)(y0 + 1) < (unsigned)HW;
    int vm = (int)(vx0 && vy0) | ((int)(vx1 && vy0) << 1) |
             ((int)(vx0 && vy1) << 2) | ((int)(vx1 && vy1) << 3);
    int i00 = y0 * HW + x0;
    marr[p] = make_int2(i00, vm);
    int key = min(max(i00, 0), NPLANE - 1) >> 9;
    atomicAdd(&hist[key], 1);
  }
  __syncthreads();
  int v = hist[tid];
  pref[tid] = v;
  __syncthreads();
  for (int d = 1; d < 512; d <<= 1) {
    int t = (tid >= d) ? pref[tid - d] : 0;
    __syncthreads();
    pref[tid] += t;
    __syncthreads();
  }
  hist[tid] = pref[tid] - v;  // exclusive prefix -> running offsets
  __syncthreads();
#pragma unroll
  for (int q = 0; q < 8; ++q) {
    int p = q * 512 + tid;
    int2 mm = marr[p];
    int key = min(max(mm.x, 0), NPLANE - 1) >> 9;
    int pos = atomicAdd(&hist[key], 1);
    perm[(size_t)b * NP + pos] = p;
    m2s[(size_t)b * NP + pos] = mm;
    float x = pxr[q] * 512.0f - 0.5f;
    float y = pyr[q] * 512.0f - 0.5f;
    float wx = x - floorf(x), wy = y - floorf(y);
    wtss[(size_t)b * NP + pos] =
        make_float4((1.0f - wx) * (1.0f - wy), wx * (1.0f - wy),
                    (1.0f - wx) * wy, wx * wy);
  }
}

// ---------------------------------------------------------------------------
// K4: gather in sorted point order. Interior fast path (vm==15, ~99.2% of
// points): each row pair loaded as one 8-byte memcpy (dwordx2). Boundary
// points keep the exact scalar predicated path. One channel per block
// (R14 showed CPB>1 loses TLP). (R13-verified, byte-identical.)
// ---------------------------------------------------------------------------
__global__ __launch_bounds__(256) void k_gather6(
    const float* __restrict__ fine, const float* __restrict__ coarse,
    const int2* __restrict__ m2s, const float4* __restrict__ wtss,
    float* __restrict__ featsT) {
  int c = blockIdx.x % CIN;
  int rem = blockIdx.x / CIN;
  int b = rem & (BATCH - 1);
  int part = rem >> 2;
  const float* plane = (c < CF_CH)
                           ? fine + ((size_t)b * CF_CH + c) * NPLANE
                           : coarse + ((size_t)b * CC_CH + (c - CF_CH)) * NPLANE;
  const int2* m2b = m2s + (size_t)b * NP;
  const float4* wtsb = wtss + (size_t)b * NP;
  float* outrow = featsT + (size_t)c * M_TOT + (size_t)b * NP;
  int s0 = part * (NP / GCH_SPLIT);
#pragma unroll
  for (int q = 0; q < NP / GCH_SPLIT / 256; ++q) {
    int s = s0 + q * 256 + (int)threadIdx.x;
    int2 mm = m2b[s];
    float4 w = wtsb[s];
    float r;
    if (mm.y == 15) {
      float2 ra, rb;
      __builtin_memcpy(&ra, &plane[mm.x], 8);
      __builtin_memcpy(&rb, &plane[mm.x + HW], 8);
      r = (((ra.x * w.x) + (ra.y * w.y)) + (rb.x * w.z)) + (rb.y * w.w);
    } else {
      const float* bp = plane + mm.x;
      float t00 = 0.0f, t10 = 0.0f, t01 = 0.0f, t11 = 0.0f;
      if (mm.y & 1) t00 = bp[0] * w.x;
      if (mm.y & 2) t10 = bp[1] * w.y;
      if (mm.y & 4) t01 = bp[HW] * w.z;
      if (mm.y & 8) t11 = bp[HW + 1] * w.w;
      r = ((t00 + t10) + t01) + t11;
    }
    outrow[s] = r;
  }
}

// ---------------------------------------------------------------------------
// K5: GEMM layer 1 from transposed A (At[k][m]), C[M][256] row-major.
// 128x64 tile, BK=32, 256 threads, 8x4 acc. (R13-verified, byte-identical.)
// ---------------------------------------------------------------------------
__global__ __launch_bounds__(256) void k_gemm1_At(const float* __restrict__ At,
                                                  const float* __restrict__ W,
                                                  const float* __restrict__ bias,
                                                  float* __restrict__ C) {
  __shared__ __align__(16) float As[32][132];
  __shared__ __align__(16) float Bs[32][68];
  const int bx = blockIdx.x & 3;   // N tile (256/64)
  const int by = blockIdx.x >> 2;  // M tile (16384/128)
  const int tid = threadIdx.x;
  const int tn = tid & 15, tm = tid >> 4;
  const int m_base = by * 128, n_base = bx * 64;
  float acc[8][4] = {};
  for (int k0 = 0; k0 < CIN; k0 += 32) {
#pragma unroll
    for (int r = 0; r < 4; ++r) {  // A: 32k x 128m = 1024 float4
      int t = tid + r * 256;
      int kk = t >> 5, mg = (t & 31) * 4;
      *(float4*)&As[kk][mg] =
          *(const float4*)&At[(size_t)(k0 + kk) * M_TOT + m_base + mg];
    }
#pragma unroll
    for (int r = 0; r < 2; ++r) {  // B: 64n x 32k
      int t = tid + r * 256;
      int row = t >> 3, cg = (t & 7) * 4;
      float4 vw = *(const float4*)&W[(size_t)(n_base + row) * CIN + k0 + cg];
      Bs[cg + 0][row] = vw.x;
      Bs[cg + 1][row] = vw.y;
      Bs[cg + 2][row] = vw.z;
      Bs[cg + 3][row] = vw.w;
    }
    __syncthreads();
#pragma unroll
    for (int kk = 0; kk < 32; ++kk) {
      float a[8];
      *(float4*)&a[0] = *(const float4*)&As[kk][tm * 8];
      *(float4*)&a[4] = *(const float4*)&As[kk][tm * 8 + 4];
      float4 b4 = *(const float4*)&Bs[kk][tn * 4];
      float bw[4] = {b4.x, b4.y, b4.z, b4.w};
#pragma unroll
      for (int i = 0; i < 8; ++i)
#pragma unroll
        for (int j = 0; j < 4; ++j) acc[i][j] = fmaf(a[i], bw[j], acc[i][j]);
    }
    __syncthreads();
  }
  float bs[4];
#pragma unroll
  for (int j = 0; j < 4; ++j) bs[j] = bias[n_base + tn * 4 + j];
#pragma unroll
  for (int i = 0; i < 8; ++i) {
    float4 o;
    o.x = fmaxf(acc[i][0] + bs[0], 0.0f);
    o.y = fmaxf(acc[i][1] + bs[1], 0.0f);
    o.z = fmaxf(acc[i][2] + bs[2], 0.0f);
    o.w = fmaxf(acc[i][3] + bs[3], 0.0f);
    *(float4*)&C[(size_t)(m_base + tm * 8 + i) * HID + n_base + tn * 4] = o;
  }
}

// ---------------------------------------------------------------------------
// K6: GEMM layer 2 (row-major A), 128x64 tile, 8x4 acc. (R13-verified,
// byte-identical.)
// ---------------------------------------------------------------------------
template <int K>
__global__ __launch_bounds__(256) void k_gemm_relu(const float* __restrict__ A,
                                                   const float* __restrict__ W,
                                                   const float* __restrict__ bias,
                                                   float* __restrict__ C) {
  __shared__ __align__(16) float As[32][132];
  __shared__ __align__(16) float Bs[32][68];
  const int bx = blockIdx.x & 3;
  const int by = blockIdx.x >> 2;
  const int tid = threadIdx.x;
  const int tn = tid & 15, tm = tid >> 4;
  const int m_base = by * 128, n_base = bx * 64;
  float acc[8][4] = {};
  for (int k0 = 0; k0 < K; k0 += 32) {
#pragma unroll
    for (int r = 0; r < 4; ++r) {  // A: 128 rows x 32 k
      int t = tid + r * 256;
      int row = t >> 3, cg = (t & 7) * 4;
      float4 va = *(const float4*)&A[(size_t)(m_base + row) * K + k0 + cg];
      As[cg + 0][row] = va.x;
      As[cg + 1][row] = va.y;
      As[cg + 2][row] = va.z;
      As[cg + 3][row] = va.w;
    }
#pragma unroll
    for (int r = 0; r < 2; ++r) {  // B: 64n x 32k
      int t = tid + r * 256;
      int row = t >> 3, cg = (t & 7) * 4;
      float4 vw = *(const float4*)&W[(size_t)(n_base + row) * K + k0 + cg];
      Bs[cg + 0][row] = vw.x;
      Bs[cg + 1][row] = vw.y;
      Bs[cg + 2][row] = vw.z;
      Bs[cg + 3][row] = vw.w;
    }
    __syncthreads();
#pragma unroll
    for (int kk = 0; kk < 32; ++kk) {
      float a[8];
      *(float4*)&a[0] = *(const float4*)&As[kk][tm * 8];
      *(float4*)&a[4] = *(const float4*)&As[kk][tm * 8 + 4];
      float4 b4 = *(const float4*)&Bs[kk][tn * 4];
      float bw[4] = {b4.x, b4.y, b4.z, b4.w};
#pragma unroll
      for (int i = 0; i < 8; ++i)
#pragma unroll
        for (int j = 0; j < 4; ++j) acc[i][j] = fmaf(a[i], bw[j], acc[i][j]);
    }
    __syncthreads();
  }
  float bs[4];
#pragma unroll
  for (int j = 0; j < 4; ++j) bs[j] = bias[n_base + tn * 4 + j];
#pragma unroll
  for (int i = 0; i < 8; ++i) {
    float4 o;
    o.x = fmaxf(acc[i][0] + bs[0], 0.0f);
    o.y = fmaxf(acc[i][1] + bs[1], 0.0f);
    o.z = fmaxf(acc[i][2] + bs[2], 0.0f);
    o.w = fmaxf(acc[i][3] + bs[3], 0.0f);
    *(float4*)&C[(size_t)(m_base + tm * 8 + i) * HID + n_base + tn * 4] = o;
  }
}

// ---------------------------------------------------------------------------
// K7: final layer, 4 outputs per point, shuffle reduce; un-permutes sorted
// order on the output scatter (R9/R12-verified, byte-identical).
// ---------------------------------------------------------------------------
__global__ __launch_bounds__(256) void k_out(const float* __restrict__ h,
                                             const float* __restrict__ W3,
                                             const float* __restrict__ b3,
                                             const int* __restrict__ perm,
                                             float* __restrict__ out) {
  int gp = blockIdx.x * 4 + (threadIdx.x >> 6);
  int lane = threadIdx.x & 63;
  const float* hr = h + (size_t)gp * HID;
  float4 hv = *(const float4*)&hr[lane * 4];
  float s[4];
#pragma unroll
  for (int o = 0; o < 4; ++o) {
    float4 w = *(const float4*)&W3[o * HID + lane * 4];
    s[o] = hv.x * w.x + hv.y * w.y + hv.z * w.z + hv.w * w.w;
  }
#pragma unroll
  for (int off = 32; off; off >>= 1)
#pragma unroll
    for (int o = 0; o < 4; ++o) s[o] += __shfl_xor(s[o], off, 64);
  if (lane == 0) {
    int b = gp / NP, ns = gp % NP;
    int n = perm[(size_t)b * NP + ns];
#pragma unroll
    for (int o = 0; o < 4; ++o)
      out[((size_t)b * OUTC + o) * NP + n] = s[o] + b3[o];
  }
}

extern "C" void kernel_launch(void* const* d_in, const int* in_sizes, int n_in,
                              void* d_out, int out_size, void* d_ws, size_t ws_size,
                              hipStream_t stream) {
  const float* fine = (const float*)d_in[0];
  const float* coarse = (const float*)d_in[1];
  const float* logits = (const float*)d_in[2];
  const float* rand_points = (const float*)d_in[3];
  const float* rand_extra = (const float*)d_in[4];
  const float* W1 = (const float*)d_in[5];
  const float* b1 = (const float*)d_in[6];
  const float* W2 = (const float*)d_in[7];
  const float* b2 = (const float*)d_in[8];
  const float* W3 = (const float*)d_in[9];
  const float* b3 = (const float*)d_in[10];
  float* out = (float*)d_out;

  float* out_logits = out;
  float* out_points = out + (size_t)BATCH * OUTC * NP;

  // ws layout (bytes): u | m2s | wtss | perm | featsT | h1 | h2
  char* ws = (char*)d_ws;
  float* u = (float*)(ws + 0);               // 196608
  int2* m2s = (int2*)(ws + 196608);          // 131072
  float4* wtss = (float4*)(ws + 327680);     // 262144
  int* perm = (int*)(ws + 589824);           // 65536
  float* featsT = (float*)(ws + 655360);     // 12582912
  float* h1 = (float*)(ws + 13238272);       // 16777216
  float* h2 = (float*)(ws + 30015488);       // 16777216

  k_uncert_extra<<<(BATCH * NS + BATCH * NR + 255) / 256, 256, 0, stream>>>(
      logits, rand_points, rand_extra, u, out_points);
  k_select<<<BATCH * (NS / 256), 256, 0, stream>>>(u, rand_points, out_points);
  k_meta<<<BATCH, 512, 0, stream>>>(out_points, m2s, wtss, perm);
  k_gather6<<<CIN * BATCH * GCH_SPLIT, 256, 0, stream>>>(fine, coarse, m2s,
                                                         wtss, featsT);
  k_gemm1_At<<<(M_TOT / 128) * 4, 256, 0, stream>>>(featsT, W1, b1, h1);
  k_gemm_relu<HID><<<(M_TOT / 128) * 4, 256, 0, stream>>>(h1, W2, b2, h2);
  k_out<<<M_TOT / 4, 256, 0, stream>>>(h2, W3, b3, perm, out_logits);
}